// Round 2
// baseline (570.234 us; speedup 1.0000x reference)
//
#include <hip/hip_runtime.h>
#include <hip/hip_bf16.h>

typedef __bf16 bf16_t;
typedef __bf16 bf16x8 __attribute__((ext_vector_type(8)));
typedef float f32x4 __attribute__((ext_vector_type(4)));
typedef unsigned int u32;

#define MFMA16(a, b, c) __builtin_amdgcn_mfma_f32_16x16x32_bf16(a, b, c, 0, 0, 0)

// ---------------------------------------------------------------------------
// dtype probe: scan 128 uint16s of x. If x is fp32, the low-16-bit mantissa
// halves decode (as bf16) to random exponent fields; P(all < 0x90) ~ 1e-16.
// Genuine bf16 N(0,1) data never has exponent >= 0x90 (|v| >= 2^17).
// ---------------------------------------------------------------------------
__device__ inline int detect_f32(const void* xp) {
    const u32* p = (const u32*)xp;
    int f = 0;
#pragma unroll
    for (int i = 0; i < 64; ++i) {
        u32 v = p[i];
        f |= (int)(((v >> 7) & 0xFFu) >= 0x90u);
        f |= (int)(((v >> 23) & 0xFFu) >= 0x90u);
    }
    return f;
}

__device__ inline float ldf(const void* p, int i, int f32) {
    return f32 ? ((const float*)p)[i] : (float)((const bf16_t*)p)[i];
}

// ---------------------------------------------------------------------------
// prep_fold: W'[j][c] = qkv_w[j][c] * norm_g[c]  (bf16)
//            u[j] = sum_c g[c]*W[j][c]; t[j] = sum_c b[c]*W[j][c] + qkv_b[j]
// qkv_j(token) = r*(x@W'^T - mu*u_j) + t_j  with per-token (mu, r).
// ---------------------------------------------------------------------------
__global__ void prep_fold(const void* __restrict__ x, const void* __restrict__ qw,
                          const void* __restrict__ qb, const void* __restrict__ ng,
                          const void* __restrict__ nb, bf16_t* __restrict__ Wp,
                          float* __restrict__ uu, float* __restrict__ tt) {
    const int f32 = detect_f32(x);
    int j = blockIdx.x;      // 0..383
    int l = threadIdx.x;     // 0..63
    float g0 = ldf(ng, l, f32),  g1 = ldf(ng, l + 64, f32);
    float b0 = ldf(nb, l, f32),  b1 = ldf(nb, l + 64, f32);
    float w0 = ldf(qw, j * 128 + l, f32), w1 = ldf(qw, j * 128 + l + 64, f32);
    float wg0 = w0 * g0, wg1 = w1 * g1;
    Wp[j * 128 + l] = (bf16_t)wg0;
    Wp[j * 128 + l + 64] = (bf16_t)wg1;
    float su = wg0 + wg1;
    float st = w0 * b0 + w1 * b1;
#pragma unroll
    for (int off = 32; off >= 1; off >>= 1) {
        su += __shfl_xor(su, off, 64);
        st += __shfl_xor(st, off, 64);
    }
    if (l == 0) { uu[j] = su; tt[j] = st + ldf(qb, j, f32); }
}

// ---------------------------------------------------------------------------
// prep_pos: DynamicPosBias MLP, 961 rows: (bh,bw) -> 8 -> 8 -> 8 -> 4 heads
// ---------------------------------------------------------------------------
__device__ inline void ln8(float* p, const void* g, const void* b, int f32) {
    float m = 0.f;
#pragma unroll
    for (int i = 0; i < 8; ++i) m += p[i];
    m *= 0.125f;
    float v = 0.f;
#pragma unroll
    for (int i = 0; i < 8; ++i) { float d = p[i] - m; v += d * d; }
    v *= 0.125f;
    float r = rsqrtf(v + 1e-5f);
#pragma unroll
    for (int i = 0; i < 8; ++i)
        p[i] = fmaxf((p[i] - m) * r * ldf(g, i, f32) + ldf(b, i, f32), 0.f);
}

__global__ void prep_pos(const void* __restrict__ x,
                         const void* __restrict__ ppw, const void* __restrict__ ppb,
                         const void* __restrict__ l1g, const void* __restrict__ l1b,
                         const void* __restrict__ f1w, const void* __restrict__ f1b,
                         const void* __restrict__ l2g, const void* __restrict__ l2b,
                         const void* __restrict__ f2w, const void* __restrict__ f2b,
                         const void* __restrict__ l3g, const void* __restrict__ l3b,
                         const void* __restrict__ f3w, const void* __restrict__ f3b,
                         float* __restrict__ pos) {
    const int f32 = detect_f32(x);
    int r = blockIdx.x * 128 + threadIdx.x;
    if (r >= 961) return;
    float bh = (float)(r / 31) - 15.f;
    float bw = (float)(r % 31) - 15.f;
    float p[8], q[8];
#pragma unroll
    for (int i = 0; i < 8; ++i)
        p[i] = ldf(ppw, i * 2, f32) * bh + ldf(ppw, i * 2 + 1, f32) * bw + ldf(ppb, i, f32);
    ln8(p, l1g, l1b, f32);  // LN + relu
#pragma unroll
    for (int o = 0; o < 8; ++o) {
        float s = ldf(f1b, o, f32);
#pragma unroll
        for (int i = 0; i < 8; ++i) s += p[i] * ldf(f1w, o * 8 + i, f32);
        q[o] = s;
    }
    ln8(q, l2g, l2b, f32);
#pragma unroll
    for (int o = 0; o < 8; ++o) {
        float s = ldf(f2b, o, f32);
#pragma unroll
        for (int i = 0; i < 8; ++i) s += q[i] * ldf(f2w, o * 8 + i, f32);
        p[o] = s;
    }
    ln8(p, l3g, l3b, f32);
#pragma unroll
    for (int o = 0; o < 4; ++o) {
        float s = ldf(f3b, o, f32);
#pragma unroll
        for (int i = 0; i < 8; ++i) s += p[i] * ldf(f3w, o * 8 + i, f32);
        pos[r * 4 + o] = s;
    }
}

// ---------------------------------------------------------------------------
// prep_bias: bias[h][i][j] = pos[rel(i,j)][h]   (fp32, [4][256][256])
// ---------------------------------------------------------------------------
__global__ void prep_bias(const float* __restrict__ pos, float* __restrict__ bias) {
    int i = blockIdx.x;    // query token in window
    int j = threadIdx.x;   // key token in window
    int rel = ((i >> 4) - (j >> 4) + 15) * 31 + ((i & 15) - (j & 15) + 15);
    f32x4 p4 = *(const f32x4*)(pos + rel * 4);
#pragma unroll
    for (int h = 0; h < 4; ++h) bias[(h << 16) + (i << 8) + j] = p4[h];
}

// ---------------------------------------------------------------------------
// Main fused kernel: one block per (window, head). 256 threads = 4 waves.
// Wave w owns query rows [64w, 64w+64).
// ---------------------------------------------------------------------------
__global__ __launch_bounds__(256, 2) void win_attn(
    const void* __restrict__ xv, const bf16_t* __restrict__ Wp,
    const float* __restrict__ uu, const float* __restrict__ tt,
    const float* __restrict__ biasg, const float* __restrict__ posg,
    const int bias_mode, void* __restrict__ outv) {
    __shared__ __align__(16) bf16_t k_s[256 * 40];    // k  [token][d]
    __shared__ __align__(16) bf16_t vT_s[32 * 264];   // v^T[d][token]
    __shared__ __align__(16) bf16_t Pb_s[4 * 64 * 40];// wave-private scratch
    __shared__ float mu_s[256], r_s[256];
    __shared__ float uu_s[96], tt_s[96];

    const int f32 = detect_f32(xv);
    const int tid = threadIdx.x;
    const int lane = tid & 63;
    const int w = tid >> 6;
    const int head = blockIdx.x & 3;
    const int wi = blockIdx.x >> 2;
    const int bi = wi >> 8;
    const int wh = (wi >> 4) & 15, ww = wi & 15;
    const int xbase = bi * (256 * 256 * 128);
    const int rbase = (lane >> 4) * 4;

    if (tid < 96) {
        int sel = tid >> 5, dd = tid & 31;
        int j = sel * 128 + head * 32 + dd;
        uu_s[tid] = uu[j];
        tt_s[tid] = tt[j];
    }

    // ---- phase A: per-token mean / rstd (4 lanes per token, coalesced) ----
#pragma unroll
    for (int it = 0; it < 4; ++it) {
        int i = w * 64 + it * 16 + (lane >> 2);
        int gi = xbase + ((wh * 16 + (i >> 4)) * 256 + ww * 16 + (i & 15)) * 128;
        float s = 0.f, s2 = 0.f;
        if (f32) {
            const f32x4* p4 = (const f32x4*)((const float*)xv + gi);
#pragma unroll
            for (int c = 0; c < 4; ++c) {
                f32x4 a = p4[(c * 4 + (lane & 3)) * 2];
                f32x4 b = p4[(c * 4 + (lane & 3)) * 2 + 1];
#pragma unroll
                for (int e = 0; e < 4; ++e) {
                    s += a[e] + b[e]; s2 += a[e] * a[e] + b[e] * b[e];
                }
            }
        } else {
            const bf16_t* p = (const bf16_t*)xv + gi;
#pragma unroll
            for (int c = 0; c < 4; ++c) {
                bf16x8 v = *(const bf16x8*)(p + (c * 4 + (lane & 3)) * 8);
#pragma unroll
                for (int e = 0; e < 8; ++e) { float f = (float)v[e]; s += f; s2 += f * f; }
            }
        }
        s  += __shfl_xor(s, 1, 4);  s  += __shfl_xor(s, 2, 4);
        s2 += __shfl_xor(s2, 1, 4); s2 += __shfl_xor(s2, 2, 4);
        if ((lane & 3) == 0) {
            float mu = s * (1.f / 128.f);
            float var = s2 * (1.f / 128.f) - mu * mu;
            mu_s[i] = mu;
            r_s[i] = rsqrtf(var + 1e-5f);
        }
    }
    __syncthreads();

    // ---- phase B: qkv GEMM this head: M=256 (64/wave), N=96, K=128 ----
    f32x4 acc[6][4];
#pragma unroll
    for (int nt = 0; nt < 6; ++nt)
#pragma unroll
        for (int mt = 0; mt < 4; ++mt) acc[nt][mt] = f32x4{0.f, 0.f, 0.f, 0.f};

    int axi[4];
#pragma unroll
    for (int mt = 0; mt < 4; ++mt) {
        int i = w * 64 + mt * 16 + (lane & 15);
        axi[mt] = xbase + ((wh * 16 + (i >> 4)) * 256 + ww * 16 + (i & 15)) * 128;
    }
    const bf16_t* bw[6];
#pragma unroll
    for (int nt = 0; nt < 6; ++nt) {
        int sel = nt >> 1;
        int jg = sel * 128 + head * 32 + (nt & 1) * 16 + (lane & 15);
        bw[nt] = Wp + jg * 128;
    }
#pragma unroll
    for (int ks = 0; ks < 4; ++ks) {
        int ko = ks * 32 + (lane >> 4) * 8;
        bf16x8 af[4], bfr[6];
        if (f32) {
#pragma unroll
            for (int mt = 0; mt < 4; ++mt) {
                const float* pp = (const float*)xv + axi[mt] + ko;
                f32x4 u0 = *(const f32x4*)pp;
                f32x4 u1 = *(const f32x4*)(pp + 4);
                bf16x8 t;
#pragma unroll
                for (int e = 0; e < 4; ++e) { t[e] = (bf16_t)u0[e]; t[e + 4] = (bf16_t)u1[e]; }
                af[mt] = t;
            }
        } else {
#pragma unroll
            for (int mt = 0; mt < 4; ++mt)
                af[mt] = *(const bf16x8*)((const bf16_t*)xv + axi[mt] + ko);
        }
#pragma unroll
        for (int nt = 0; nt < 6; ++nt) bfr[nt] = *(const bf16x8*)(bw[nt] + ko);
#pragma unroll
        for (int nt = 0; nt < 6; ++nt)
#pragma unroll
            for (int mt = 0; mt < 4; ++mt)
                acc[nt][mt] = MFMA16(af[mt], bfr[nt], acc[nt][mt]);
    }

    // fixup (apply LN) + scatter q->Pb (wave-private), k->k_s, v->vT_s
    const float qscale = 0.17677669529663689f;  // 1/sqrt(32)
#pragma unroll
    for (int nt = 0; nt < 6; ++nt) {
        int sel = nt >> 1;
        int col = (nt & 1) * 16 + (lane & 15);  // 0..31 inside q/k/v
        float uj = uu_s[sel * 32 + col];
        float tj = tt_s[sel * 32 + col];
#pragma unroll
        for (int mt = 0; mt < 4; ++mt)
#pragma unroll
            for (int rg = 0; rg < 4; ++rg) {
                int rl = w * 64 + mt * 16 + rbase + rg;  // local token (row)
                float val = r_s[rl] * (acc[nt][mt][rg] - mu_s[rl] * uj) + tj;
                if (sel == 0) {
                    Pb_s[w * 2560 + (mt * 16 + rbase + rg) * 40 + col] = (bf16_t)(val * qscale);
                } else if (sel == 1) {
                    k_s[rl * 40 + col] = (bf16_t)val;
                } else {
                    vT_s[col * 264 + rl] = (bf16_t)val;
                }
            }
    }
    __syncthreads();

    // q A-frags out of wave-private scratch (C-layout -> A-layout round trip)
    bf16x8 qf[4];
#pragma unroll
    for (int mt = 0; mt < 4; ++mt)
        qf[mt] = *(const bf16x8*)(Pb_s + w * 2560 + (mt * 16 + (lane & 15)) * 40 + (lane >> 4) * 8);

    // ---- phase C: flash attention over 8 key blocks of 32 ----
    f32x4 Oa[2][4];
#pragma unroll
    for (int np = 0; np < 2; ++np)
#pragma unroll
        for (int mt = 0; mt < 4; ++mt) Oa[np][mt] = f32x4{0.f, 0.f, 0.f, 0.f};
    float mst[16], lst[16];
#pragma unroll
    for (int z = 0; z < 16; ++z) { mst[z] = -3.0e38f; lst[z] = 0.f; }

    const float* brow = biasg + (head << 16);
    const f32x4 zero4 = {0.f, 0.f, 0.f, 0.f};

    for (int kb = 0; kb < 8; ++kb) {
        bf16x8 kf[2];
#pragma unroll
        for (int nt = 0; nt < 2; ++nt)
            kf[nt] = *(const bf16x8*)(k_s + (kb * 32 + nt * 16 + (lane & 15)) * 40 + (lane >> 4) * 8);
        f32x4 S[4][2];
#pragma unroll
        for (int mt = 0; mt < 4; ++mt)
#pragma unroll
            for (int nt = 0; nt < 2; ++nt)
                S[mt][nt] = MFMA16(qf[mt], kf[nt], zero4);

#pragma unroll
        for (int mt = 0; mt < 4; ++mt)
#pragma unroll
            for (int rg = 0; rg < 4; ++rg) {
                int i = w * 64 + mt * 16 + rbase + rg;
                int jj = kb * 32 + (lane & 15);
                float b0, b1;
                if (bias_mode) {
                    b0 = brow[(i << 8) + jj];
                    b1 = brow[(i << 8) + jj + 16];
                } else {
                    int j1 = jj + 16;
                    int r0 = ((i >> 4) - (jj >> 4) + 15) * 31 + ((i & 15) - (jj & 15) + 15);
                    int r1 = ((i >> 4) - (j1 >> 4) + 15) * 31 + ((i & 15) - (j1 & 15) + 15);
                    b0 = posg[r0 * 4 + head];
                    b1 = posg[r1 * 4 + head];
                }
                float s0 = S[mt][0][rg] + b0;
                float s1 = S[mt][1][rg] + b1;
                float mx = fmaxf(s0, s1);
#pragma unroll
                for (int off = 1; off < 16; off <<= 1) mx = fmaxf(mx, __shfl_xor(mx, off, 16));
                float mo = mst[mt * 4 + rg];
                float mn = fmaxf(mo, mx);
                float al = __expf(mo - mn);
                float p0 = __expf(s0 - mn);
                float p1 = __expf(s1 - mn);
                float rs = p0 + p1;
#pragma unroll
                for (int off = 1; off < 16; off <<= 1) rs += __shfl_xor(rs, off, 16);
                lst[mt * 4 + rg] = al * lst[mt * 4 + rg] + rs;
                mst[mt * 4 + rg] = mn;
                Oa[0][mt][rg] *= al;
                Oa[1][mt][rg] *= al;
                bf16_t* pw = Pb_s + w * 2560 + (mt * 16 + rbase + rg) * 40;
                pw[lane & 15] = (bf16_t)p0;
                pw[16 + (lane & 15)] = (bf16_t)p1;
            }
        __syncthreads();  // order P writes (C-layout) vs A-frag reads

        bf16x8 pf[4], vf[2];
#pragma unroll
        for (int mt = 0; mt < 4; ++mt)
            pf[mt] = *(const bf16x8*)(Pb_s + w * 2560 + (mt * 16 + (lane & 15)) * 40 + (lane >> 4) * 8);
#pragma unroll
        for (int np = 0; np < 2; ++np)
            vf[np] = *(const bf16x8*)(vT_s + (np * 16 + (lane & 15)) * 264 + kb * 32 + (lane >> 4) * 8);
#pragma unroll
        for (int np = 0; np < 2; ++np)
#pragma unroll
            for (int mt = 0; mt < 4; ++mt)
                Oa[np][mt] = MFMA16(pf[mt], vf[np], Oa[np][mt]);
    }

    // ---- epilogue: O/l + residual, write (bf16 or fp32 per probe) ----
#pragma unroll
    for (int mt = 0; mt < 4; ++mt)
#pragma unroll
        for (int rg = 0; rg < 4; ++rg) {
            int i = w * 64 + mt * 16 + rbase + rg;
            float inv = 1.f / lst[mt * 4 + rg];
            int go = xbase + ((wh * 16 + (i >> 4)) * 256 + ww * 16 + (i & 15)) * 128 + head * 32;
            int c0 = lane & 15;
            float o0 = Oa[0][mt][rg] * inv + ldf(xv, go + c0, f32);
            float o1 = Oa[1][mt][rg] * inv + ldf(xv, go + 16 + c0, f32);
            if (f32) {
                ((float*)outv)[go + c0] = o0;
                ((float*)outv)[go + 16 + c0] = o1;
            } else {
                ((bf16_t*)outv)[go + c0] = (bf16_t)o0;
                ((bf16_t*)outv)[go + 16 + c0] = (bf16_t)o1;
            }
        }
}

extern "C" void kernel_launch(void* const* d_in, const int* in_sizes, int n_in,
                              void* d_out, int out_size, void* d_ws, size_t ws_size,
                              hipStream_t stream) {
    const void* x   = d_in[0];
    const void* ng  = d_in[1];
    const void* nb  = d_in[2];
    const void* qw  = d_in[3];
    const void* qb  = d_in[4];
    const void* ppw = d_in[5];
    const void* ppb = d_in[6];
    const void* l1g = d_in[7];
    const void* l1b = d_in[8];
    const void* f1w = d_in[9];
    const void* f1b = d_in[10];
    const void* l2g = d_in[11];
    const void* l2b = d_in[12];
    const void* f2w = d_in[13];
    const void* f2b = d_in[14];
    const void* l3g = d_in[15];
    const void* l3b = d_in[16];
    const void* f3w = d_in[17];
    const void* f3b = d_in[18];

    char* ws = (char*)d_ws;
    bf16_t* Wp  = (bf16_t*)ws;            // 384*128*2   = 98304 B
    float* uu   = (float*)(ws + 98304);   // 384*4       = 1536 B
    float* tt   = (float*)(ws + 99840);   // 384*4       = 1536 B
    float* pos  = (float*)(ws + 101376);  // 961*4*4     = 15376 B
    float* bias = (float*)(ws + 116752);  // 4*256*256*4 = 1 MB
    const size_t need_full = 116752 + 4 * 256 * 256 * 4;
    const int bias_mode = (ws_size >= need_full) ? 1 : 0;  // constant per session

    prep_fold<<<dim3(384), dim3(64), 0, stream>>>(x, qw, qb, ng, nb, Wp, uu, tt);
    prep_pos<<<dim3(8), dim3(128), 0, stream>>>(x, ppw, ppb, l1g, l1b, f1w, f1b,
                                                l2g, l2b, f2w, f2b, l3g, l3b,
                                                f3w, f3b, pos);
    if (bias_mode)
        prep_bias<<<dim3(256), dim3(256), 0, stream>>>(pos, bias);
    win_attn<<<dim3(2048), dim3(256), 0, stream>>>(x, Wp, uu, tt, bias, pos,
                                                   bias_mode, d_out);
}

// Round 3
// 431.549 us; speedup vs baseline: 1.3214x; 1.3214x over previous
//
#include <hip/hip_runtime.h>
#include <hip/hip_bf16.h>

typedef __bf16 bf16_t;
typedef __bf16 bf16x8 __attribute__((ext_vector_type(8)));
typedef __bf16 bf16x2 __attribute__((ext_vector_type(2)));
typedef float f32x4 __attribute__((ext_vector_type(4)));
typedef float f32x2 __attribute__((ext_vector_type(2)));
typedef unsigned int u32;

#define MFMA16(a, b, c) __builtin_amdgcn_mfma_f32_16x16x32_bf16(a, b, c, 0, 0, 0)

__device__ inline float ldf(const void* p, int i, int f32) {
    return f32 ? ((const float*)p)[i] : (float)((const bf16_t*)p)[i];
}

// ---------------------------------------------------------------------------
// probe_dtype: one wave; if x is fp32, mantissa halves decode (as bf16) to
// huge exponents. Writes flag once; everyone else reads 1 word.
// ---------------------------------------------------------------------------
__global__ void probe_dtype(const u32* __restrict__ x, int* __restrict__ flags) {
    u32 v = x[threadIdx.x];
    int f = (((v >> 7) & 0xFFu) >= 0x90u) || (((v >> 23) & 0xFFu) >= 0x90u);
    f = __any(f);
    if (threadIdx.x == 0) flags[0] = f ? 1 : 0;
}

// ---------------------------------------------------------------------------
// conv_norm: xn[token] = LayerNorm_noaffine(x[token]) as bf16. One wave/token.
// ---------------------------------------------------------------------------
__global__ __launch_bounds__(256) void conv_norm(const void* __restrict__ xv,
                                                 const int* __restrict__ flags,
                                                 u32* __restrict__ xn) {
    const int f32 = flags[0];
    int t = blockIdx.x * 4 + (threadIdx.x >> 6);
    int lane = threadIdx.x & 63;
    float f0, f1;
    if (f32) {
        f32x2 v = *(const f32x2*)((const float*)xv + t * 128 + lane * 2);
        f0 = v[0]; f1 = v[1];
    } else {
        u32 w = ((const u32*)xv)[t * 64 + lane];
        f0 = __builtin_bit_cast(float, w << 16);
        f1 = __builtin_bit_cast(float, w & 0xFFFF0000u);
    }
    float s = f0 + f1, s2 = f0 * f0 + f1 * f1;
#pragma unroll
    for (int off = 32; off >= 1; off >>= 1) {
        s += __shfl_xor(s, off, 64);
        s2 += __shfl_xor(s2, off, 64);
    }
    float mu = s * (1.f / 128.f);
    float r = rsqrtf(s2 * (1.f / 128.f) - mu * mu + 1e-5f);
    bf16x2 h = { (bf16_t)((f0 - mu) * r), (bf16_t)((f1 - mu) * r) };
    xn[t * 64 + lane] = __builtin_bit_cast(u32, h);
}

// ---------------------------------------------------------------------------
// prep_fold: W'[j][c] = qkv_w[j][c]*g[c] (bf16); u[j]=sum g*W; t[j]=sum b*W+qb
// ---------------------------------------------------------------------------
__global__ void prep_fold(const int* __restrict__ flags, const void* __restrict__ qw,
                          const void* __restrict__ qb, const void* __restrict__ ng,
                          const void* __restrict__ nb, bf16_t* __restrict__ Wp,
                          float* __restrict__ uu, float* __restrict__ tt) {
    const int f32 = flags[0];
    int j = blockIdx.x;
    int l = threadIdx.x;
    float g0 = ldf(ng, l, f32),  g1 = ldf(ng, l + 64, f32);
    float b0 = ldf(nb, l, f32),  b1 = ldf(nb, l + 64, f32);
    float w0 = ldf(qw, j * 128 + l, f32), w1 = ldf(qw, j * 128 + l + 64, f32);
    float wg0 = w0 * g0, wg1 = w1 * g1;
    Wp[j * 128 + l] = (bf16_t)wg0;
    Wp[j * 128 + l + 64] = (bf16_t)wg1;
    float su = wg0 + wg1;
    float st = w0 * b0 + w1 * b1;
#pragma unroll
    for (int off = 32; off >= 1; off >>= 1) {
        su += __shfl_xor(su, off, 64);
        st += __shfl_xor(st, off, 64);
    }
    if (l == 0) { uu[j] = su; tt[j] = st + ldf(qb, j, f32); }
}

// ---------------------------------------------------------------------------
// prep_pos: DynamicPosBias MLP, 961 rows
// ---------------------------------------------------------------------------
__device__ inline void ln8(float* p, const void* g, const void* b, int f32) {
    float m = 0.f;
#pragma unroll
    for (int i = 0; i < 8; ++i) m += p[i];
    m *= 0.125f;
    float v = 0.f;
#pragma unroll
    for (int i = 0; i < 8; ++i) { float d = p[i] - m; v += d * d; }
    v *= 0.125f;
    float r = rsqrtf(v + 1e-5f);
#pragma unroll
    for (int i = 0; i < 8; ++i)
        p[i] = fmaxf((p[i] - m) * r * ldf(g, i, f32) + ldf(b, i, f32), 0.f);
}

__global__ void prep_pos(const int* __restrict__ flags,
                         const void* __restrict__ ppw, const void* __restrict__ ppb,
                         const void* __restrict__ l1g, const void* __restrict__ l1b,
                         const void* __restrict__ f1w, const void* __restrict__ f1b,
                         const void* __restrict__ l2g, const void* __restrict__ l2b,
                         const void* __restrict__ f2w, const void* __restrict__ f2b,
                         const void* __restrict__ l3g, const void* __restrict__ l3b,
                         const void* __restrict__ f3w, const void* __restrict__ f3b,
                         float* __restrict__ pos) {
    const int f32 = flags[0];
    int r = blockIdx.x * 128 + threadIdx.x;
    if (r >= 961) return;
    float bh = (float)(r / 31) - 15.f;
    float bw = (float)(r % 31) - 15.f;
    float p[8], q[8];
#pragma unroll
    for (int i = 0; i < 8; ++i)
        p[i] = ldf(ppw, i * 2, f32) * bh + ldf(ppw, i * 2 + 1, f32) * bw + ldf(ppb, i, f32);
    ln8(p, l1g, l1b, f32);
#pragma unroll
    for (int o = 0; o < 8; ++o) {
        float s = ldf(f1b, o, f32);
#pragma unroll
        for (int i = 0; i < 8; ++i) s += p[i] * ldf(f1w, o * 8 + i, f32);
        q[o] = s;
    }
    ln8(q, l2g, l2b, f32);
#pragma unroll
    for (int o = 0; o < 8; ++o) {
        float s = ldf(f2b, o, f32);
#pragma unroll
        for (int i = 0; i < 8; ++i) s += q[i] * ldf(f2w, o * 8 + i, f32);
        p[o] = s;
    }
    ln8(p, l3g, l3b, f32);
#pragma unroll
    for (int o = 0; o < 4; ++o) {
        float s = ldf(f3b, o, f32);
#pragma unroll
        for (int i = 0; i < 8; ++i) s += p[i] * ldf(f3w, o * 8 + i, f32);
        pos[r * 4 + o] = s;
    }
}

// ---------------------------------------------------------------------------
// prep_bias: bias[h][i][j] = pos[rel(i,j)][h]   (fp32, [4][256][256])
// ---------------------------------------------------------------------------
__global__ void prep_bias(const float* __restrict__ pos, float* __restrict__ bias) {
    int i = blockIdx.x;
    int j = threadIdx.x;
    int rel = ((i >> 4) - (j >> 4) + 15) * 31 + ((i & 15) - (j & 15) + 15);
    f32x4 p4 = *(const f32x4*)(pos + rel * 4);
#pragma unroll
    for (int h = 0; h < 4; ++h) bias[(h << 16) + (i << 8) + j] = p4[h];
}

// ---------------------------------------------------------------------------
// win_attn<XN>: one block per (window, head); 4 waves; wave owns 64 q-rows.
// XN=1: A = prenormalized bf16 xn (no stats, no fixup). XN=0: fallback on raw x.
// No-max softmax (scores bounded ~|1|), deferred l reduction, no kb barriers.
// ---------------------------------------------------------------------------
template <int XN>
__global__ __launch_bounds__(256, 2) void win_attn(
    const void* __restrict__ xv, const bf16_t* __restrict__ xnp,
    const bf16_t* __restrict__ Wp, const float* __restrict__ uu,
    const float* __restrict__ tt, const float* __restrict__ biasg,
    const float* __restrict__ posg, const int* __restrict__ flags,
    const int bias_mode, void* __restrict__ outv) {
    __shared__ __align__(16) bf16_t k_s[256 * 40];     // k  [token][d]
    __shared__ __align__(16) bf16_t vT_s[32 * 280];    // v^T[d][token], pad 280
    __shared__ __align__(16) bf16_t Pb_s[4 * 64 * 40]; // wave-private q/P scratch
    __shared__ float mu_s[256], r_s[256];              // XN=0 only
    __shared__ float uu_s[96], tt_s[96];

    const int f32 = flags[0];
    const int tid = threadIdx.x;
    const int lane = tid & 63;
    const int w = tid >> 6;
    const int head = blockIdx.x & 3;
    const int wi = blockIdx.x >> 2;
    const int bi = wi >> 8;
    const int wh = (wi >> 4) & 15, ww = wi & 15;
    const int xbase = bi * (256 * 256 * 128);
    const int rbase = (lane >> 4) * 4;

    if (tid < 96) {
        int sel = tid >> 5, dd = tid & 31;
        int j = sel * 128 + head * 32 + dd;
        tt_s[tid] = tt[j];
        if (!XN) uu_s[tid] = uu[j];
    }

    if (!XN) {
        // per-token mean/rstd (4 lanes per token)
#pragma unroll
        for (int it = 0; it < 4; ++it) {
            int i = w * 64 + it * 16 + (lane >> 2);
            int gi = xbase + ((wh * 16 + (i >> 4)) * 256 + ww * 16 + (i & 15)) * 128;
            float s = 0.f, s2 = 0.f;
            if (f32) {
                const f32x4* p4 = (const f32x4*)((const float*)xv + gi);
#pragma unroll
                for (int c = 0; c < 4; ++c) {
                    f32x4 a = p4[(c * 4 + (lane & 3)) * 2];
                    f32x4 b = p4[(c * 4 + (lane & 3)) * 2 + 1];
#pragma unroll
                    for (int e = 0; e < 4; ++e) { s += a[e] + b[e]; s2 += a[e] * a[e] + b[e] * b[e]; }
                }
            } else {
                const bf16_t* p = (const bf16_t*)xv + gi;
#pragma unroll
                for (int c = 0; c < 4; ++c) {
                    bf16x8 v = *(const bf16x8*)(p + (c * 4 + (lane & 3)) * 8);
#pragma unroll
                    for (int e = 0; e < 8; ++e) { float f = (float)v[e]; s += f; s2 += f * f; }
                }
            }
            s  += __shfl_xor(s, 1, 4);  s  += __shfl_xor(s, 2, 4);
            s2 += __shfl_xor(s2, 1, 4); s2 += __shfl_xor(s2, 2, 4);
            if ((lane & 3) == 0) {
                float mu = s * (1.f / 128.f);
                mu_s[i] = mu;
                r_s[i] = rsqrtf(s2 * (1.f / 128.f) - mu * mu + 1e-5f);
            }
        }
    }

    // ---- qkv GEMM this head: M=256 (64/wave), N=96, K=128 ----
    f32x4 acc[6][4];
#pragma unroll
    for (int nt = 0; nt < 6; ++nt)
#pragma unroll
        for (int mt = 0; mt < 4; ++mt) acc[nt][mt] = f32x4{0.f, 0.f, 0.f, 0.f};

    int axi[4];
#pragma unroll
    for (int mt = 0; mt < 4; ++mt) {
        int i = w * 64 + mt * 16 + (lane & 15);
        axi[mt] = xbase + ((wh * 16 + (i >> 4)) * 256 + ww * 16 + (i & 15)) * 128;
    }
    const bf16_t* bw[6];
#pragma unroll
    for (int nt = 0; nt < 6; ++nt) {
        int sel = nt >> 1;
        int jg = sel * 128 + head * 32 + (nt & 1) * 16 + (lane & 15);
        bw[nt] = Wp + jg * 128;
    }
#pragma unroll
    for (int ks = 0; ks < 4; ++ks) {
        int ko = ks * 32 + (lane >> 4) * 8;
        bf16x8 af[4], bfr[6];
        if (XN) {
#pragma unroll
            for (int mt = 0; mt < 4; ++mt)
                af[mt] = *(const bf16x8*)(xnp + axi[mt] + ko);
        } else if (f32) {
#pragma unroll
            for (int mt = 0; mt < 4; ++mt) {
                const float* pp = (const float*)xv + axi[mt] + ko;
                f32x4 u0 = *(const f32x4*)pp;
                f32x4 u1 = *(const f32x4*)(pp + 4);
                bf16x8 t;
#pragma unroll
                for (int e = 0; e < 4; ++e) { t[e] = (bf16_t)u0[e]; t[e + 4] = (bf16_t)u1[e]; }
                af[mt] = t;
            }
        } else {
#pragma unroll
            for (int mt = 0; mt < 4; ++mt)
                af[mt] = *(const bf16x8*)((const bf16_t*)xv + axi[mt] + ko);
        }
#pragma unroll
        for (int nt = 0; nt < 6; ++nt) bfr[nt] = *(const bf16x8*)(bw[nt] + ko);
#pragma unroll
        for (int nt = 0; nt < 6; ++nt)
#pragma unroll
            for (int mt = 0; mt < 4; ++mt)
                acc[nt][mt] = MFMA16(af[mt], bfr[nt], acc[nt][mt]);
    }
    __syncthreads();  // tt_s (+ mu/r for XN=0) visible

    // fixup + scatter q->Pb (wave-private), k->k_s, v->vT_s
    const float qscale = 0.17677669529663689f;  // 1/sqrt(32)
#pragma unroll
    for (int nt = 0; nt < 6; ++nt) {
        int sel = nt >> 1;
        int col = (nt & 1) * 16 + (lane & 15);
        float tj = tt_s[sel * 32 + col];
        float uj = XN ? 0.f : uu_s[sel * 32 + col];
#pragma unroll
        for (int mt = 0; mt < 4; ++mt)
#pragma unroll
            for (int rg = 0; rg < 4; ++rg) {
                int rl = w * 64 + mt * 16 + rbase + rg;
                float val;
                if (XN) val = acc[nt][mt][rg] + tj;
                else    val = r_s[rl] * (acc[nt][mt][rg] - mu_s[rl] * uj) + tj;
                if (sel == 0) {
                    Pb_s[w * 2560 + (mt * 16 + rbase + rg) * 40 + col] = (bf16_t)(val * qscale);
                } else if (sel == 1) {
                    k_s[rl * 40 + col] = (bf16_t)val;
                } else {
                    vT_s[col * 280 + rl] = (bf16_t)val;
                }
            }
    }
    __syncthreads();  // k_s / vT_s cross-wave visibility

    // q A-frags (wave-private round trip)
    bf16x8 qf[4];
#pragma unroll
    for (int mt = 0; mt < 4; ++mt)
        qf[mt] = *(const bf16x8*)(Pb_s + w * 2560 + (mt * 16 + (lane & 15)) * 40 + (lane >> 4) * 8);

    // ---- attention over 8 key blocks of 32, no-max softmax ----
    f32x4 Oa[2][4];
#pragma unroll
    for (int np = 0; np < 2; ++np)
#pragma unroll
        for (int mt = 0; mt < 4; ++mt) Oa[np][mt] = f32x4{0.f, 0.f, 0.f, 0.f};
    float lst[16];
#pragma unroll
    for (int z = 0; z < 16; ++z) lst[z] = 0.f;

    const float* brow = biasg + (head << 16);
    const f32x4 zero4 = {0.f, 0.f, 0.f, 0.f};

    for (int kb = 0; kb < 8; ++kb) {
        bf16x8 kf[2];
#pragma unroll
        for (int nt = 0; nt < 2; ++nt)
            kf[nt] = *(const bf16x8*)(k_s + (kb * 32 + nt * 16 + (lane & 15)) * 40 + (lane >> 4) * 8);
        f32x4 S[4][2];
#pragma unroll
        for (int mt = 0; mt < 4; ++mt)
#pragma unroll
            for (int nt = 0; nt < 2; ++nt)
                S[mt][nt] = MFMA16(qf[mt], kf[nt], zero4);

#pragma unroll
        for (int mt = 0; mt < 4; ++mt)
#pragma unroll
            for (int rg = 0; rg < 4; ++rg) {
                int i = w * 64 + mt * 16 + rbase + rg;
                int jj = kb * 32 + (lane & 15);
                float b0, b1;
                if (bias_mode) {
                    b0 = brow[(i << 8) + jj];
                    b1 = brow[(i << 8) + jj + 16];
                } else {
                    int j1 = jj + 16;
                    int r0 = ((i >> 4) - (jj >> 4) + 15) * 31 + ((i & 15) - (jj & 15) + 15);
                    int r1 = ((i >> 4) - (j1 >> 4) + 15) * 31 + ((i & 15) - (j1 & 15) + 15);
                    b0 = posg[r0 * 4 + head];
                    b1 = posg[r1 * 4 + head];
                }
                float p0 = __expf(S[mt][0][rg] + b0);
                float p1 = __expf(S[mt][1][rg] + b1);
                lst[mt * 4 + rg] += p0 + p1;
                bf16_t* pw = Pb_s + w * 2560 + (mt * 16 + rbase + rg) * 40;
                pw[lane & 15] = (bf16_t)p0;
                pw[16 + (lane & 15)] = (bf16_t)p1;
            }
        // wave-private Pb: no barrier needed
        bf16x8 pf[4], vf[2];
#pragma unroll
        for (int mt = 0; mt < 4; ++mt)
            pf[mt] = *(const bf16x8*)(Pb_s + w * 2560 + (mt * 16 + (lane & 15)) * 40 + (lane >> 4) * 8);
#pragma unroll
        for (int np = 0; np < 2; ++np)
            vf[np] = *(const bf16x8*)(vT_s + (np * 16 + (lane & 15)) * 280 + kb * 32 + (lane >> 4) * 8);
#pragma unroll
        for (int np = 0; np < 2; ++np)
#pragma unroll
            for (int mt = 0; mt < 4; ++mt)
                Oa[np][mt] = MFMA16(pf[mt], vf[np], Oa[np][mt]);
    }

    // ---- epilogue: reduce l, O/l + residual, store ----
#pragma unroll
    for (int mt = 0; mt < 4; ++mt)
#pragma unroll
        for (int rg = 0; rg < 4; ++rg) {
            float l = lst[mt * 4 + rg];
#pragma unroll
            for (int off = 1; off < 16; off <<= 1) l += __shfl_xor(l, off, 16);
            float inv = 1.f / l;
            int i = w * 64 + mt * 16 + rbase + rg;
            int go = xbase + ((wh * 16 + (i >> 4)) * 256 + ww * 16 + (i & 15)) * 128 + head * 32;
            int c0 = lane & 15;
            float o0 = Oa[0][mt][rg] * inv + ldf(xv, go + c0, f32);
            float o1 = Oa[1][mt][rg] * inv + ldf(xv, go + 16 + c0, f32);
            if (f32) {
                ((float*)outv)[go + c0] = o0;
                ((float*)outv)[go + 16 + c0] = o1;
            } else {
                ((bf16_t*)outv)[go + c0] = (bf16_t)o0;
                ((bf16_t*)outv)[go + 16 + c0] = (bf16_t)o1;
            }
        }
}

extern "C" void kernel_launch(void* const* d_in, const int* in_sizes, int n_in,
                              void* d_out, int out_size, void* d_ws, size_t ws_size,
                              hipStream_t stream) {
    const void* x   = d_in[0];
    const void* ng  = d_in[1];
    const void* nb  = d_in[2];
    const void* qw  = d_in[3];
    const void* qb  = d_in[4];
    const void* ppw = d_in[5];
    const void* ppb = d_in[6];
    const void* l1g = d_in[7];
    const void* l1b = d_in[8];
    const void* f1w = d_in[9];
    const void* f1b = d_in[10];
    const void* l2g = d_in[11];
    const void* l2b = d_in[12];
    const void* f2w = d_in[13];
    const void* f2b = d_in[14];
    const void* l3g = d_in[15];
    const void* l3b = d_in[16];
    const void* f3w = d_in[17];
    const void* f3b = d_in[18];

    char* ws = (char*)d_ws;
    int*    flags = (int*)ws;                     // @0, 16 B
    bf16_t* Wp    = (bf16_t*)(ws + 16);           // 98304 B
    float*  uu    = (float*)(ws + 98320);         // 1536 B
    float*  tt    = (float*)(ws + 99856);         // 1536 B
    float*  pos   = (float*)(ws + 101392);        // 15376 B
    float*  bias  = (float*)(ws + 116768);        // 1048576 B
    bf16_t* xn    = (bf16_t*)(ws + 1165344);      // 33554432 B
    const int bias_mode = (ws_size >= 1165344) ? 1 : 0;
    const int use_xn    = (ws_size >= 1165344 + 33554432u) ? 1 : 0;

    probe_dtype<<<dim3(1), dim3(64), 0, stream>>>((const u32*)x, flags);
    if (use_xn)
        conv_norm<<<dim3(32768), dim3(256), 0, stream>>>(x, flags, (u32*)xn);
    prep_fold<<<dim3(384), dim3(64), 0, stream>>>(flags, qw, qb, ng, nb, Wp, uu, tt);
    prep_pos<<<dim3(8), dim3(128), 0, stream>>>(flags, ppw, ppb, l1g, l1b, f1w, f1b,
                                                l2g, l2b, f2w, f2b, l3g, l3b,
                                                f3w, f3b, pos);
    if (bias_mode)
        prep_bias<<<dim3(256), dim3(256), 0, stream>>>(pos, bias);
    if (use_xn)
        win_attn<1><<<dim3(2048), dim3(256), 0, stream>>>(x, xn, Wp, uu, tt, bias,
                                                          pos, flags, bias_mode, d_out);
    else
        win_attn<0><<<dim3(2048), dim3(256), 0, stream>>>(x, xn, Wp, uu, tt, bias,
                                                          pos, flags, bias_mode, d_out);
}

// Round 4
// 321.780 us; speedup vs baseline: 1.7721x; 1.3411x over previous
//
#include <hip/hip_runtime.h>
#include <hip/hip_bf16.h>

typedef __bf16 bf16_t;
typedef __bf16 bf16x2 __attribute__((ext_vector_type(2)));
typedef __bf16 bf16x4 __attribute__((ext_vector_type(4)));
typedef __bf16 bf16x8 __attribute__((ext_vector_type(8)));
typedef float f32x2 __attribute__((ext_vector_type(2)));
typedef float f32x4 __attribute__((ext_vector_type(4)));
typedef unsigned int u32;

#define MFMA16(a, b, c) __builtin_amdgcn_mfma_f32_16x16x32_bf16(a, b, c, 0, 0, 0)

__device__ inline float ldf(const void* p, int i, int f32) {
    return f32 ? ((const float*)p)[i] : (float)((const bf16_t*)p)[i];
}

// ---------------------------------------------------------------------------
// probe_dtype: one wave decides fp32 vs bf16, writes flags[0].
// ---------------------------------------------------------------------------
__global__ void probe_dtype(const u32* __restrict__ x, int* __restrict__ flags) {
    u32 v = x[threadIdx.x];
    int f = (((v >> 7) & 0xFFu) >= 0x90u) || (((v >> 23) & 0xFFu) >= 0x90u);
    f = __any(f);
    if (threadIdx.x == 0) flags[0] = f ? 1 : 0;
}

// ---------------------------------------------------------------------------
// conv_norm: xn[token] = LayerNorm_noaffine(x[token]) as bf16. One wave/token.
// ---------------------------------------------------------------------------
__global__ __launch_bounds__(256) void conv_norm(const void* __restrict__ xv,
                                                 const int* __restrict__ flags,
                                                 u32* __restrict__ xn) {
    const int f32 = flags[0];
    int t = blockIdx.x * 4 + (threadIdx.x >> 6);
    int lane = threadIdx.x & 63;
    float f0, f1;
    if (f32) {
        f32x2 v = *(const f32x2*)((const float*)xv + t * 128 + lane * 2);
        f0 = v[0]; f1 = v[1];
    } else {
        u32 w = ((const u32*)xv)[t * 64 + lane];
        f0 = __builtin_bit_cast(float, w << 16);
        f1 = __builtin_bit_cast(float, w & 0xFFFF0000u);
    }
    float s = f0 + f1, s2 = f0 * f0 + f1 * f1;
#pragma unroll
    for (int off = 32; off >= 1; off >>= 1) {
        s += __shfl_xor(s, off, 64);
        s2 += __shfl_xor(s2, off, 64);
    }
    float mu = s * (1.f / 128.f);
    float r = rsqrtf(s2 * (1.f / 128.f) - mu * mu + 1e-5f);
    bf16x2 h = { (bf16_t)((f0 - mu) * r), (bf16_t)((f1 - mu) * r) };
    xn[t * 64 + lane] = __builtin_bit_cast(u32, h);
}

// ---------------------------------------------------------------------------
// prep_fp: blocks 0..383 -> fold qkv_w row j with LN gamma/beta;
//          blocks 384..399 -> DynamicPosBias MLP rows (64 each).
// ---------------------------------------------------------------------------
__device__ inline void ln8(float* p, const void* g, const void* b, int f32) {
    float m = 0.f;
#pragma unroll
    for (int i = 0; i < 8; ++i) m += p[i];
    m *= 0.125f;
    float v = 0.f;
#pragma unroll
    for (int i = 0; i < 8; ++i) { float d = p[i] - m; v += d * d; }
    v *= 0.125f;
    float r = rsqrtf(v + 1e-5f);
#pragma unroll
    for (int i = 0; i < 8; ++i)
        p[i] = fmaxf((p[i] - m) * r * ldf(g, i, f32) + ldf(b, i, f32), 0.f);
}

__global__ void prep_fp(const int* __restrict__ flags,
                        const void* __restrict__ qw, const void* __restrict__ qb,
                        const void* __restrict__ ng, const void* __restrict__ nb,
                        bf16_t* __restrict__ Wp, float* __restrict__ uu,
                        float* __restrict__ tt,
                        const void* __restrict__ ppw, const void* __restrict__ ppb,
                        const void* __restrict__ l1g, const void* __restrict__ l1b,
                        const void* __restrict__ f1w, const void* __restrict__ f1b,
                        const void* __restrict__ l2g, const void* __restrict__ l2b,
                        const void* __restrict__ f2w, const void* __restrict__ f2b,
                        const void* __restrict__ l3g, const void* __restrict__ l3b,
                        const void* __restrict__ f3w, const void* __restrict__ f3b,
                        float* __restrict__ pos) {
    const int f32 = flags[0];
    if (blockIdx.x < 384) {
        int j = blockIdx.x;
        int l = threadIdx.x;
        float g0 = ldf(ng, l, f32),  g1 = ldf(ng, l + 64, f32);
        float b0 = ldf(nb, l, f32),  b1 = ldf(nb, l + 64, f32);
        float w0 = ldf(qw, j * 128 + l, f32), w1 = ldf(qw, j * 128 + l + 64, f32);
        float wg0 = w0 * g0, wg1 = w1 * g1;
        Wp[j * 128 + l] = (bf16_t)wg0;
        Wp[j * 128 + l + 64] = (bf16_t)wg1;
        float su = wg0 + wg1;
        float st = w0 * b0 + w1 * b1;
#pragma unroll
        for (int off = 32; off >= 1; off >>= 1) {
            su += __shfl_xor(su, off, 64);
            st += __shfl_xor(st, off, 64);
        }
        if (l == 0) { uu[j] = su; tt[j] = st + ldf(qb, j, f32); }
        return;
    }
    int r = (blockIdx.x - 384) * 64 + threadIdx.x;
    if (r >= 961) return;
    float bh = (float)(r / 31) - 15.f;
    float bw = (float)(r % 31) - 15.f;
    float p[8], q[8];
#pragma unroll
    for (int i = 0; i < 8; ++i)
        p[i] = ldf(ppw, i * 2, f32) * bh + ldf(ppw, i * 2 + 1, f32) * bw + ldf(ppb, i, f32);
    ln8(p, l1g, l1b, f32);
#pragma unroll
    for (int o = 0; o < 8; ++o) {
        float s = ldf(f1b, o, f32);
#pragma unroll
        for (int i = 0; i < 8; ++i) s += p[i] * ldf(f1w, o * 8 + i, f32);
        q[o] = s;
    }
    ln8(q, l2g, l2b, f32);
#pragma unroll
    for (int o = 0; o < 8; ++o) {
        float s = ldf(f2b, o, f32);
#pragma unroll
        for (int i = 0; i < 8; ++i) s += q[i] * ldf(f2w, o * 8 + i, f32);
        p[o] = s;
    }
    ln8(p, l3g, l3b, f32);
#pragma unroll
    for (int o = 0; o < 4; ++o) {
        float s = ldf(f3b, o, f32);
#pragma unroll
        for (int i = 0; i < 8; ++i) s += p[i] * ldf(f3w, o * 8 + i, f32);
        pos[r * 4 + o] = s;
    }
}

// ---------------------------------------------------------------------------
// win_attn: one block per (window, head); 4 waves; wave owns 64 q-tokens.
// S^T = K Q^T orientation: softmax sums run along registers; P^T B-frags via
// ds_bpermute (no LDS P scratch, no barriers in kb loop). 4 blocks/CU.
// ---------------------------------------------------------------------------
template <int XN>
__global__ __launch_bounds__(256, 4) void win_attn(
    const void* __restrict__ xv, const bf16_t* __restrict__ xnp,
    const bf16_t* __restrict__ Wp, const float* __restrict__ uu,
    const float* __restrict__ tt, const float* __restrict__ posg,
    const int* __restrict__ flags, void* __restrict__ outv) {
    __shared__ __align__(16) bf16_t k_s[256 * 40];   // q-stage then K [token][d]
    __shared__ __align__(16) bf16_t vT_s[32 * 264];  // V^T [d][token]
    __shared__ bf16_t pos_s[962];
    __shared__ float tt_s[96];
    __shared__ float uu_s[XN ? 2 : 96];
    __shared__ float mu_s[XN ? 2 : 256];
    __shared__ float r_s[XN ? 2 : 256];

    const int f32 = flags[0];
    const int tid = threadIdx.x;
    const int lane = tid & 63;
    const int w = tid >> 6;
    const int l15 = lane & 15;
    const int quad = lane >> 4;
    const int head = blockIdx.x & 3;
    const int wi = blockIdx.x >> 2;
    const int bi = wi >> 8;
    const int wh = (wi >> 4) & 15, ww = wi & 15;
    const int xbase = bi * (256 * 256 * 128);

    if (tid < 96) {
        int sg = tid >> 5, dd = tid & 31;
        tt_s[tid] = tt[sg * 128 + head * 32 + dd];
        if (!XN) uu_s[tid] = uu[sg * 128 + head * 32 + dd];
    }
    for (int r = tid; r < 961; r += 256) pos_s[r] = (bf16_t)posg[r * 4 + head];

    if (!XN) {
#pragma unroll
        for (int it = 0; it < 4; ++it) {
            int i = w * 64 + it * 16 + (lane >> 2);
            int gi = xbase + ((wh * 16 + (i >> 4)) * 256 + ww * 16 + (i & 15)) * 128;
            float s = 0.f, s2 = 0.f;
            if (f32) {
                const f32x4* p4 = (const f32x4*)((const float*)xv + gi);
#pragma unroll
                for (int c = 0; c < 4; ++c) {
                    f32x4 a = p4[(c * 4 + (lane & 3)) * 2];
                    f32x4 b = p4[(c * 4 + (lane & 3)) * 2 + 1];
#pragma unroll
                    for (int e = 0; e < 4; ++e) { s += a[e] + b[e]; s2 += a[e] * a[e] + b[e] * b[e]; }
                }
            } else {
                const bf16_t* p = (const bf16_t*)xv + gi;
#pragma unroll
                for (int c = 0; c < 4; ++c) {
                    bf16x8 v = *(const bf16x8*)(p + (c * 4 + (lane & 3)) * 8);
#pragma unroll
                    for (int e = 0; e < 8; ++e) { float f = (float)v[e]; s += f; s2 += f * f; }
                }
            }
            s  += __shfl_xor(s, 1, 4);  s  += __shfl_xor(s, 2, 4);
            s2 += __shfl_xor(s2, 1, 4); s2 += __shfl_xor(s2, 2, 4);
            if ((lane & 3) == 0) {
                float mu = s * (1.f / 128.f);
                mu_s[i] = mu;
                r_s[i] = rsqrtf(s2 * (1.f / 128.f) - mu * mu + 1e-5f);
            }
        }
    }
    __syncthreads();  // tt_s / pos_s (/stats) ready

    // ---- QKV GEMM, sel-outer (keeps acc at 32 VGPRs) ----
    int axi[4];
#pragma unroll
    for (int mt = 0; mt < 4; ++mt) {
        int i = w * 64 + mt * 16 + l15;
        axi[mt] = xbase + ((wh * 16 + (i >> 4)) * 256 + ww * 16 + (i & 15)) * 128;
    }
    const float qscale = 0.17677669529663689f;  // 1/sqrt(32)
    bf16x8 qB[4];

#pragma unroll 1
    for (int sel = 0; sel < 3; ++sel) {
        f32x4 acc[2][4];
#pragma unroll
        for (int nt = 0; nt < 2; ++nt)
#pragma unroll
            for (int mt = 0; mt < 4; ++mt) acc[nt][mt] = f32x4{0.f, 0.f, 0.f, 0.f};
        const bf16_t* bw0 = Wp + (sel * 128 + head * 32 + l15) * 128;
        const bf16_t* bw1 = bw0 + 16 * 128;
#pragma unroll
        for (int ks = 0; ks < 4; ++ks) {
            int ko = ks * 32 + quad * 8;
            bf16x8 af[4];
            if (XN) {
#pragma unroll
                for (int mt = 0; mt < 4; ++mt)
                    af[mt] = *(const bf16x8*)(xnp + axi[mt] + ko);
            } else if (f32) {
#pragma unroll
                for (int mt = 0; mt < 4; ++mt) {
                    const float* pp = (const float*)xv + axi[mt] + ko;
                    f32x4 u0 = *(const f32x4*)pp;
                    f32x4 u1 = *(const f32x4*)(pp + 4);
                    bf16x8 t;
#pragma unroll
                    for (int e = 0; e < 4; ++e) { t[e] = (bf16_t)u0[e]; t[e + 4] = (bf16_t)u1[e]; }
                    af[mt] = t;
                }
            } else {
#pragma unroll
                for (int mt = 0; mt < 4; ++mt)
                    af[mt] = *(const bf16x8*)((const bf16_t*)xv + axi[mt] + ko);
            }
            bf16x8 b0 = *(const bf16x8*)(bw0 + ko);
            bf16x8 b1 = *(const bf16x8*)(bw1 + ko);
#pragma unroll
            for (int mt = 0; mt < 4; ++mt) {
                acc[0][mt] = MFMA16(af[mt], b0, acc[0][mt]);
                acc[1][mt] = MFMA16(af[mt], b1, acc[1][mt]);
            }
        }
        // fixup + scatter
#pragma unroll
        for (int nt = 0; nt < 2; ++nt) {
            int d = nt * 16 + l15;
            float tj = tt_s[sel * 32 + d];
            float uj = XN ? 0.f : uu_s[sel * 32 + d];
#pragma unroll
            for (int mt = 0; mt < 4; ++mt)
#pragma unroll
                for (int rg = 0; rg < 4; ++rg) {
                    int token = w * 64 + mt * 16 + quad * 4 + rg;
                    float val;
                    if (XN) val = acc[nt][mt][rg] + tj;
                    else    val = r_s[token] * (acc[nt][mt][rg] - mu_s[token] * uj) + tj;
                    if (sel == 0)      k_s[token * 40 + d] = (bf16_t)(val * qscale);
                    else if (sel == 1) k_s[token * 40 + d] = (bf16_t)val;
                    else               vT_s[d * 264 + token] = (bf16_t)val;
                }
        }
        if (sel == 0) {
            // q B-frags out of wave-private rows, then let K overwrite them
#pragma unroll
            for (int qt = 0; qt < 4; ++qt)
                qB[qt] = *(const bf16x8*)(k_s + (w * 64 + qt * 16 + l15) * 40 + quad * 8);
            __syncthreads();  // WAR guard (q reads done before K scatter lands)
        }
    }
    __syncthreads();  // K / V^T visible to all waves

    // ---- kb loop: S^T = K Q^T, bpermute P^T, O^T = V^T P^T ----
    f32x4 Oa[2][4];
#pragma unroll
    for (int np = 0; np < 2; ++np)
#pragma unroll
        for (int qt = 0; qt < 4; ++qt) Oa[np][qt] = f32x4{0.f, 0.f, 0.f, 0.f};
    float lsum[4] = {0.f, 0.f, 0.f, 0.f};

    const f32x4 zero4 = {0.f, 0.f, 0.f, 0.f};
    const int idxA = ((2 * (quad & 1)) * 16 + l15) * 4;
    const int idxB = idxA + 64;
    const bool hi_nt = (lane & 32) != 0;   // quads 2,3 pull from nt=1
    const int vinner = l15 + 15 - quad * 4;

    for (int kb = 0; kb < 8; ++kb) {
        u32 Pd[2][4][2];
#pragma unroll
        for (int nt = 0; nt < 2; ++nt) {
            bf16x8 kf = *(const bf16x8*)(k_s + (kb * 32 + nt * 16 + l15) * 40 + quad * 8);
            f32x4 S[4];
#pragma unroll
            for (int qt = 0; qt < 4; ++qt) S[qt] = MFMA16(kf, qB[qt], zero4);
#pragma unroll
            for (int qt = 0; qt < 4; ++qt) {
                int souter = (w * 4 + qt - kb * 2 - nt + 15) * 31;
                float p[4];
#pragma unroll
                for (int rg = 0; rg < 4; ++rg) {
                    float b = (float)pos_s[souter + vinner - rg];
                    p[rg] = __expf(S[qt][rg] + b);
                }
                lsum[qt] += (p[0] + p[1]) + (p[2] + p[3]);
                bf16x2 h0 = { (bf16_t)p[0], (bf16_t)p[1] };
                bf16x2 h1 = { (bf16_t)p[2], (bf16_t)p[3] };
                Pd[nt][qt][0] = __builtin_bit_cast(u32, h0);
                Pd[nt][qt][1] = __builtin_bit_cast(u32, h1);
            }
        }
        bf16x8 pB[4];
#pragma unroll
        for (int qt = 0; qt < 4; ++qt) {
            u32 dw[4];
#pragma unroll
            for (int half = 0; half < 2; ++half) {
                u32 a0 = (u32)__builtin_amdgcn_ds_bpermute(idxA, (int)Pd[0][qt][half]);
                u32 a1 = (u32)__builtin_amdgcn_ds_bpermute(idxA, (int)Pd[1][qt][half]);
                dw[half] = hi_nt ? a1 : a0;
                u32 b0 = (u32)__builtin_amdgcn_ds_bpermute(idxB, (int)Pd[0][qt][half]);
                u32 b1 = (u32)__builtin_amdgcn_ds_bpermute(idxB, (int)Pd[1][qt][half]);
                dw[2 + half] = hi_nt ? b1 : b0;
            }
            pB[qt] = __builtin_bit_cast(bf16x8, dw);
        }
        bf16x8 vf[2];
#pragma unroll
        for (int np = 0; np < 2; ++np)
            vf[np] = *(const bf16x8*)(vT_s + (np * 16 + l15) * 264 + kb * 32 + quad * 8);
#pragma unroll
        for (int np = 0; np < 2; ++np)
#pragma unroll
            for (int qt = 0; qt < 4; ++qt)
                Oa[np][qt] = MFMA16(vf[np], pB[qt], Oa[np][qt]);
    }

    // ---- epilogue: reduce lsum across quads, O/l + residual, store ----
    float inv[4];
#pragma unroll
    for (int qt = 0; qt < 4; ++qt) {
        float l = lsum[qt];
        l += __shfl_xor(l, 16, 64);
        l += __shfl_xor(l, 32, 64);
        inv[qt] = 1.f / l;
    }
#pragma unroll
    for (int np = 0; np < 2; ++np)
#pragma unroll
        for (int qt = 0; qt < 4; ++qt) {
            int go = xbase + ((wh * 16 + w * 4 + qt) * 256 + ww * 16 + l15) * 128 +
                     head * 32 + np * 16 + quad * 4;
            if (f32) {
                f32x4 res = *(const f32x4*)((const float*)xv + go);
                f32x4 o;
#pragma unroll
                for (int rg = 0; rg < 4; ++rg) o[rg] = Oa[np][qt][rg] * inv[qt] + res[rg];
                *(f32x4*)((float*)outv + go) = o;
            } else {
                bf16x4 res = *(const bf16x4*)((const bf16_t*)xv + go);
                bf16x4 o;
#pragma unroll
                for (int rg = 0; rg < 4; ++rg)
                    o[rg] = (bf16_t)(Oa[np][qt][rg] * inv[qt] + (float)res[rg]);
                *(bf16x4*)((bf16_t*)outv + go) = o;
            }
        }
}

extern "C" void kernel_launch(void* const* d_in, const int* in_sizes, int n_in,
                              void* d_out, int out_size, void* d_ws, size_t ws_size,
                              hipStream_t stream) {
    const void* x   = d_in[0];
    const void* ng  = d_in[1];
    const void* nb  = d_in[2];
    const void* qw  = d_in[3];
    const void* qb  = d_in[4];
    const void* ppw = d_in[5];
    const void* ppb = d_in[6];
    const void* l1g = d_in[7];
    const void* l1b = d_in[8];
    const void* f1w = d_in[9];
    const void* f1b = d_in[10];
    const void* l2g = d_in[11];
    const void* l2b = d_in[12];
    const void* f2w = d_in[13];
    const void* f2b = d_in[14];
    const void* l3g = d_in[15];
    const void* l3b = d_in[16];
    const void* f3w = d_in[17];
    const void* f3b = d_in[18];

    char* ws = (char*)d_ws;
    int*    flags = (int*)ws;                 // @0, 16 B
    bf16_t* Wp    = (bf16_t*)(ws + 16);       // 98304 B
    float*  uu    = (float*)(ws + 98320);     // 1536 B
    float*  tt    = (float*)(ws + 99856);     // 1536 B
    float*  pos   = (float*)(ws + 101392);    // 15376 B
    bf16_t* xn    = (bf16_t*)(ws + 116768);   // 33554432 B
    const int use_xn = (ws_size >= 116768 + 33554432u) ? 1 : 0;

    probe_dtype<<<dim3(1), dim3(64), 0, stream>>>((const u32*)x, flags);
    if (use_xn)
        conv_norm<<<dim3(32768), dim3(256), 0, stream>>>(x, flags, (u32*)xn);
    prep_fp<<<dim3(400), dim3(64), 0, stream>>>(flags, qw, qb, ng, nb, Wp, uu, tt,
                                                ppw, ppb, l1g, l1b, f1w, f1b,
                                                l2g, l2b, f2w, f2b, l3g, l3b,
                                                f3w, f3b, pos);
    if (use_xn)
        win_attn<1><<<dim3(2048), dim3(256), 0, stream>>>(x, xn, Wp, uu, tt, pos,
                                                          flags, d_out);
    else
        win_attn<0><<<dim3(2048), dim3(256), 0, stream>>>(x, xn, Wp, uu, tt, pos,
                                                          flags, d_out);
}